// Round 6
// baseline (999.958 us; speedup 1.0000x reference)
//
#include <hip/hip_runtime.h>
#include <hip/hip_bf16.h>

#define N_NODES 100000
#define N_EDGES 1600000
#define N_FEAT 7
#define HID 128
#define N_CLASS 5
#define N_GRAPHS 8
#define NPB 8    // nodes per block (layer1 + hidden)
#define NPW 4    // nodes per wave (hidden): 2 waves/block
#define SCAN_NBLK ((N_NODES + 1023) / 1024)   // 98

typedef __hip_bfloat16 bf16;

__device__ __forceinline__ float bflo(unsigned u) { return __uint_as_float(u << 16); }
__device__ __forceinline__ float bfhi(unsigned u) { return __uint_as_float(u & 0xFFFF0000u); }
__device__ __forceinline__ unsigned packbf(float a, float b) {
    bf16 x = __float2bfloat16(a), y = __float2bfloat16(b);
    unsigned short ux = *(unsigned short*)&x, uy = *(unsigned short*)&y;
    return (unsigned)ux | ((unsigned)uy << 16);
}

// ---------------- CSR build (dst-sorted adjacency) ----------------

__global__ void hist_kernel(const int* __restrict__ dst, int* __restrict__ deg) {
    int e = blockIdx.x * blockDim.x + threadIdx.x;
    if (e < N_EDGES) atomicAdd(&deg[dst[e]], 1);
}

__global__ __launch_bounds__(1024) void scan_phase1(const int* __restrict__ deg,
                                                    int* __restrict__ tmp,
                                                    int* __restrict__ bsum) {
    __shared__ int s[1024];
    int tid = threadIdx.x;
    int i = blockIdx.x * 1024 + tid;
    int v = (i < N_NODES) ? deg[i] : 0;
    s[tid] = v;
    __syncthreads();
    for (int off = 1; off < 1024; off <<= 1) {
        int u = (tid >= off) ? s[tid - off] : 0;
        __syncthreads();
        s[tid] += u;
        __syncthreads();
    }
    if (i < N_NODES) tmp[i] = s[tid] - v;            // exclusive
    if (tid == 1023) bsum[blockIdx.x] = s[1023];
}

__global__ __launch_bounds__(128) void scan_phase2(int* __restrict__ bsum) {
    __shared__ int s[128];
    int tid = threadIdx.x;
    int v = (tid < SCAN_NBLK) ? bsum[tid] : 0;
    s[tid] = v;
    __syncthreads();
    for (int off = 1; off < 128; off <<= 1) {
        int u = (tid >= off) ? s[tid - off] : 0;
        __syncthreads();
        s[tid] += u;
        __syncthreads();
    }
    if (tid < SCAN_NBLK) bsum[tid] = s[tid] - v;
}

__global__ __launch_bounds__(1024) void scan_phase3(const int* __restrict__ tmp,
                                                    const int* __restrict__ bsum,
                                                    int* __restrict__ rowptr,
                                                    int* __restrict__ cursor) {
    int i = blockIdx.x * 1024 + threadIdx.x;
    if (i < N_NODES) {
        int r = tmp[i] + bsum[blockIdx.x];
        rowptr[i] = r;
        cursor[i] = r;
    }
    if (i == 0) rowptr[N_NODES] = N_EDGES;
}

__global__ void scatter_kernel(const int* __restrict__ src, const int* __restrict__ dst,
                               const float* __restrict__ ea, int* __restrict__ cursor,
                               int2* __restrict__ csr) {
    int e = blockIdx.x * blockDim.x + threadIdx.x;
    if (e >= N_EDGES) return;
    int d = dst[e];
    int p = atomicAdd(&cursor[d], 1);
    csr[p] = make_int2(src[e], __float_as_int(ea[e]));
}

// ---------------- Layer 1 fused (in=7): edge-agg + GEMV ----------------

__global__ __launch_bounds__(64) void layer1(
        const float* __restrict__ x, const int2* __restrict__ csr,
        const int* __restrict__ rowptr, const float* __restrict__ We,
        const float* __restrict__ be, const float* __restrict__ W,
        const float* __restrict__ b, bf16* __restrict__ h1) {
    __shared__ float t[NPB][8];
    int L = threadIdx.x;
    int u = L & 7, m = L >> 3;
    int n0 = blockIdx.x * NPB;
    int n = n0 + m;
    int r0 = rowptr[n], r1 = rowptr[n + 1];
    float we[N_FEAT], bee[N_FEAT], p[N_FEAT];
#pragma unroll
    for (int k = 0; k < N_FEAT; ++k) { we[k] = We[k]; bee[k] = be[k]; p[k] = 0.f; }
    for (int i = r0 + u; i < r1; i += 8) {
        int2 sa = csr[i];
        float a = __int_as_float(sa.y);
        const float* xr = x + (size_t)sa.x * N_FEAT;
#pragma unroll
        for (int k = 0; k < N_FEAT; ++k) {
            float mm = xr[k] + a * we[k] + bee[k];
            p[k] += mm > 0.f ? mm : 0.f;
        }
    }
#pragma unroll
    for (int off = 1; off < 8; off <<= 1)
#pragma unroll
        for (int k = 0; k < N_FEAT; ++k) p[k] += __shfl_xor(p[k], off, 64);
    if (u == 0) {
        const float* xn = x + (size_t)n * N_FEAT;
#pragma unroll
        for (int k = 0; k < N_FEAT; ++k) t[m][k] = p[k] + xn[k];
    }
    __syncthreads();
    float w0[N_FEAT], w1[N_FEAT];
#pragma unroll
    for (int k = 0; k < N_FEAT; ++k) { w0[k] = W[k * HID + L]; w1[k] = W[k * HID + 64 + L]; }
    float bb0 = b[L], bb1 = b[64 + L];
    for (int mm = 0; mm < NPB; ++mm) {
        float s0 = bb0, s1 = bb1;
#pragma unroll
        for (int k = 0; k < N_FEAT; ++k) { float tv = t[mm][k]; s0 += tv * w0[k]; s1 += tv * w1[k]; }
        h1[((n0 + mm) << 7) + L]      = __float2bfloat16(s0 > 0.f ? s0 : 0.f);
        h1[((n0 + mm) << 7) + 64 + L] = __float2bfloat16(s1 > 0.f ? s1 : 0.f);
    }
}

// ---------------- Fused hidden layer: gather-agg + GEMV (+ optional pool) ----
// 128 threads = 2 independent waves; each wave owns NPW=4 nodes.
// Lane L owns feature pair (2L, 2L+1): one bf16x2 (4B) load per edge per lane.
// unroll 8 -> 8 gathers in flight per wave (latency/MLP-bound regime).
template <bool POOL>
__global__ __launch_bounds__(128) void hidden_layer(
        const bf16* __restrict__ hin, const int2* __restrict__ csr,
        const int* __restrict__ rowptr, const float* __restrict__ We,
        const float* __restrict__ be, const float* __restrict__ W,
        const float* __restrict__ b, bf16* __restrict__ hout,
        const int* __restrict__ batch, float* __restrict__ pool,
        float* __restrict__ cnt) {
    __shared__ float t[NPB][HID];
    int L = threadIdx.x & 63;
    int wv = threadIdx.x >> 6;
    int f = L << 1;
    int n0 = blockIdx.x * NPB + wv * NPW;   // this wave's first node
    float we0 = We[f], we1 = We[f + 1], be0 = be[f], be1 = be[f + 1];

    for (int m = 0; m < NPW; ++m) {
        int n = n0 + m;
        int r0 = rowptr[n], r1 = rowptr[n + 1];
        float a0 = 0.f, a1 = 0.f;
#pragma unroll 8
        for (int i = r0; i < r1; ++i) {
            int2 sa = csr[i];               // wave-uniform -> scalar load
            unsigned hh = *(const unsigned*)(hin + ((sa.x << 7) + f));
            float ea = __int_as_float(sa.y);
            float m0 = bflo(hh) + ea * we0 + be0;
            float m1 = bfhi(hh) + ea * we1 + be1;
            a0 += m0 > 0.f ? m0 : 0.f;
            a1 += m1 > 0.f ? m1 : 0.f;
        }
        unsigned hs = *(const unsigned*)(hin + ((n << 7) + f));
        *(float2*)&t[wv * NPW + m][f] = make_float2(a0 + bflo(hs), a1 + bfhi(hs));
    }
    __syncthreads();

    // GEMV: each wave computes its own 4 nodes (no cross-wave sharing)
    float o0[NPW], o1[NPW];
    float bb0 = b[f], bb1 = b[f + 1];
#pragma unroll
    for (int m = 0; m < NPW; ++m) { o0[m] = bb0; o1[m] = bb1; }
    for (int k = 0; k < HID; k += 2) {
        float2 wA = *(const float2*)&W[k * HID + f];
        float2 wB = *(const float2*)&W[(k + 1) * HID + f];
#pragma unroll
        for (int m = 0; m < NPW; ++m) {
            float2 tv = *(const float2*)&t[wv * NPW + m][k];   // ds_read_b64 broadcast
            o0[m] += tv.x * wA.x + tv.y * wB.x;
            o1[m] += tv.x * wA.y + tv.y * wB.y;
        }
    }

    if (!POOL) {
#pragma unroll
        for (int m = 0; m < NPW; ++m) {
            float v0 = o0[m] > 0.f ? o0[m] : 0.f;
            float v1 = o1[m] > 0.f ? o1[m] : 0.f;
            *(unsigned*)(hout + (((n0 + m) << 7) + f)) = packbf(v0, v1);
        }
    } else {
        int g = batch[n0];
        int runstart = n0;
        float p0 = 0.f, p1 = 0.f;
        for (int m = 0; m < NPW; ++m) {
            int n = n0 + m;
            int gn = batch[n];
            if (gn != g) {
                atomicAdd(&pool[g * HID + f], p0);
                atomicAdd(&pool[g * HID + f + 1], p1);
                if (L == 0) atomicAdd(&cnt[g], (float)(n - runstart));
                p0 = p1 = 0.f; g = gn; runstart = n;
            }
            p0 += o0[m] > 0.f ? o0[m] : 0.f;
            p1 += o1[m] > 0.f ? o1[m] : 0.f;
        }
        atomicAdd(&pool[g * HID + f], p0);
        atomicAdd(&pool[g * HID + f + 1], p1);
        if (L == 0) atomicAdd(&cnt[g], (float)(n0 + NPW - runstart));
    }
}

// ---------------- Head ----------------

__global__ void final_kernel(const float* __restrict__ pool, const float* __restrict__ cnt,
                             const float* __restrict__ Wlin, const float* __restrict__ blin,
                             float* __restrict__ out) {
    int idx = threadIdx.x;
    if (idx >= N_GRAPHS * N_CLASS) return;
    int g = idx / N_CLASS, c = idx % N_CLASS;
    float invc = 1.f / fmaxf(cnt[g], 1.f);
    float acc = blin[c];
    for (int j = 0; j < HID; ++j) acc += pool[g * HID + j] * invc * Wlin[j * N_CLASS + c];
    out[idx] = acc;
}

extern "C" void kernel_launch(void* const* d_in, const int* in_sizes, int n_in,
                              void* d_out, int out_size, void* d_ws, size_t ws_size,
                              hipStream_t stream) {
    const float* x    = (const float*)d_in[0];
    const int*   ei   = (const int*)d_in[1];
    const float* ea   = (const float*)d_in[2];
    const int*   batch= (const int*)d_in[3];
    const float* We1  = (const float*)d_in[4];
    const float* be1  = (const float*)d_in[5];
    const float* W1   = (const float*)d_in[6];
    const float* b1   = (const float*)d_in[7];
    const float* We2  = (const float*)d_in[8];
    const float* be2  = (const float*)d_in[9];
    const float* W2   = (const float*)d_in[10];
    const float* b2   = (const float*)d_in[11];
    const float* We3  = (const float*)d_in[12];
    const float* be3  = (const float*)d_in[13];
    const float* W3   = (const float*)d_in[14];
    const float* b3   = (const float*)d_in[15];
    const float* Wlin = (const float*)d_in[16];
    const float* blin = (const float*)d_in[17];

    const int* src = ei;
    const int* dst = ei + N_EDGES;

    // workspace layout (csr first: 8B-aligned at base)
    char* w = (char*)d_ws;
    int2*  csr    = (int2*)w;                    w += sizeof(int2) * (size_t)N_EDGES;
    bf16*  A      = (bf16*)w;                    w += sizeof(bf16) * (size_t)N_NODES * HID;
    bf16*  B      = (bf16*)w;                    w += sizeof(bf16) * (size_t)N_NODES * HID;
    float* pool   = (float*)w;                   w += sizeof(float) * N_GRAPHS * HID;
    float* cnt    = (float*)w;                   w += sizeof(float) * N_GRAPHS;
    int*   rowptr = (int*)w;                     w += sizeof(int) * (N_NODES + 1);
    int*   cursor = (int*)w;                     w += sizeof(int) * N_NODES;
    int*   deg    = (int*)w;                     w += sizeof(int) * N_NODES;
    int*   stmp   = (int*)w;                     w += sizeof(int) * N_NODES;
    int*   bsum   = (int*)w;                     w += sizeof(int) * SCAN_NBLK;

    // ---- CSR build ----
    hipMemsetAsync(deg, 0, sizeof(int) * N_NODES, stream);
    hipMemsetAsync(pool, 0, sizeof(float) * (N_GRAPHS * HID + N_GRAPHS), stream);
    hist_kernel<<<(N_EDGES + 255) / 256, 256, 0, stream>>>(dst, deg);
    scan_phase1<<<SCAN_NBLK, 1024, 0, stream>>>(deg, stmp, bsum);
    scan_phase2<<<1, 128, 0, stream>>>(bsum);
    scan_phase3<<<SCAN_NBLK, 1024, 0, stream>>>(stmp, bsum, rowptr, cursor);
    scatter_kernel<<<(N_EDGES + 255) / 256, 256, 0, stream>>>(src, dst, ea, cursor, csr);

    // ---- Layer 1 (fused) ----
    layer1<<<N_NODES / NPB, 64, 0, stream>>>(x, csr, rowptr, We1, be1, W1, b1, A);

    // ---- Layer 2: A -> B ----
    hidden_layer<false><<<N_NODES / NPB, 128, 0, stream>>>(A, csr, rowptr, We2, be2, W2, b2, B,
                                                           nullptr, nullptr, nullptr);

    // ---- Layer 3: B -> pool (fused) ----
    hidden_layer<true><<<N_NODES / NPB, 128, 0, stream>>>(B, csr, rowptr, We3, be3, W3, b3, nullptr,
                                                          batch, pool, cnt);

    // ---- Head ----
    final_kernel<<<1, 64, 0, stream>>>(pool, cnt, Wlin, blin, (float*)d_out);
}

// Round 7
// 947.974 us; speedup vs baseline: 1.0548x; 1.0548x over previous
//
#include <hip/hip_runtime.h>
#include <hip/hip_bf16.h>

#define N_NODES 100000
#define N_EDGES 1600000
#define N_FEAT 7
#define HID 128
#define N_CLASS 5
#define N_GRAPHS 8
#define NPB 8    // nodes per block (layer1 + hidden)
#define NPW 4    // nodes per wave (hidden): 2 waves/block
#define SCAN_NBLK ((N_NODES + 1023) / 1024)   // 98

typedef __hip_bfloat16 bf16;

__device__ __forceinline__ float bflo(unsigned u) { return __uint_as_float(u << 16); }
__device__ __forceinline__ float bfhi(unsigned u) { return __uint_as_float(u & 0xFFFF0000u); }
__device__ __forceinline__ unsigned packbf(float a, float b) {
    bf16 x = __float2bfloat16(a), y = __float2bfloat16(b);
    unsigned short ux = *(unsigned short*)&x, uy = *(unsigned short*)&y;
    return (unsigned)ux | ((unsigned)uy << 16);
}

// ---------------- CSR build (dst-sorted adjacency) ----------------

__global__ void hist_kernel(const int* __restrict__ dst, int* __restrict__ deg) {
    int e = blockIdx.x * blockDim.x + threadIdx.x;
    if (e < N_EDGES) atomicAdd(&deg[dst[e]], 1);
}

__global__ __launch_bounds__(1024) void scan_phase1(const int* __restrict__ deg,
                                                    int* __restrict__ tmp,
                                                    int* __restrict__ bsum) {
    __shared__ int s[1024];
    int tid = threadIdx.x;
    int i = blockIdx.x * 1024 + tid;
    int v = (i < N_NODES) ? deg[i] : 0;
    s[tid] = v;
    __syncthreads();
    for (int off = 1; off < 1024; off <<= 1) {
        int u = (tid >= off) ? s[tid - off] : 0;
        __syncthreads();
        s[tid] += u;
        __syncthreads();
    }
    if (i < N_NODES) tmp[i] = s[tid] - v;            // exclusive
    if (tid == 1023) bsum[blockIdx.x] = s[1023];
}

__global__ __launch_bounds__(128) void scan_phase2(int* __restrict__ bsum) {
    __shared__ int s[128];
    int tid = threadIdx.x;
    int v = (tid < SCAN_NBLK) ? bsum[tid] : 0;
    s[tid] = v;
    __syncthreads();
    for (int off = 1; off < 128; off <<= 1) {
        int u = (tid >= off) ? s[tid - off] : 0;
        __syncthreads();
        s[tid] += u;
        __syncthreads();
    }
    if (tid < SCAN_NBLK) bsum[tid] = s[tid] - v;
}

__global__ __launch_bounds__(1024) void scan_phase3(const int* __restrict__ tmp,
                                                    const int* __restrict__ bsum,
                                                    int* __restrict__ rowptr,
                                                    int* __restrict__ cursor) {
    int i = blockIdx.x * 1024 + threadIdx.x;
    if (i < N_NODES) {
        int r = tmp[i] + bsum[blockIdx.x];
        rowptr[i] = r;
        cursor[i] = r;
    }
    if (i == 0) rowptr[N_NODES] = N_EDGES;
}

__global__ void scatter_kernel(const int* __restrict__ src, const int* __restrict__ dst,
                               const float* __restrict__ ea, int* __restrict__ cursor,
                               int2* __restrict__ csr) {
    int e = blockIdx.x * blockDim.x + threadIdx.x;
    if (e >= N_EDGES) return;
    int d = dst[e];
    int p = atomicAdd(&cursor[d], 1);
    csr[p] = make_int2(src[e], __float_as_int(ea[e]));
}

// ---------------- Layer 1 fused (in=7): edge-agg + GEMV ----------------

__global__ __launch_bounds__(64) void layer1(
        const float* __restrict__ x, const int2* __restrict__ csr,
        const int* __restrict__ rowptr, const float* __restrict__ We,
        const float* __restrict__ be, const float* __restrict__ W,
        const float* __restrict__ b, bf16* __restrict__ h1) {
    __shared__ float t[NPB][8];
    int L = threadIdx.x;
    int u = L & 7, m = L >> 3;
    int n0 = blockIdx.x * NPB;
    int n = n0 + m;
    int r0 = rowptr[n], r1 = rowptr[n + 1];
    float we[N_FEAT], bee[N_FEAT], p[N_FEAT];
#pragma unroll
    for (int k = 0; k < N_FEAT; ++k) { we[k] = We[k]; bee[k] = be[k]; p[k] = 0.f; }
    for (int i = r0 + u; i < r1; i += 8) {
        int2 sa = csr[i];
        float a = __int_as_float(sa.y);
        const float* xr = x + (size_t)sa.x * N_FEAT;
#pragma unroll
        for (int k = 0; k < N_FEAT; ++k) {
            float mm = xr[k] + a * we[k] + bee[k];
            p[k] += mm > 0.f ? mm : 0.f;
        }
    }
#pragma unroll
    for (int off = 1; off < 8; off <<= 1)
#pragma unroll
        for (int k = 0; k < N_FEAT; ++k) p[k] += __shfl_xor(p[k], off, 64);
    if (u == 0) {
        const float* xn = x + (size_t)n * N_FEAT;
#pragma unroll
        for (int k = 0; k < N_FEAT; ++k) t[m][k] = p[k] + xn[k];
    }
    __syncthreads();
    float w0[N_FEAT], w1[N_FEAT];
#pragma unroll
    for (int k = 0; k < N_FEAT; ++k) { w0[k] = W[k * HID + L]; w1[k] = W[k * HID + 64 + L]; }
    float bb0 = b[L], bb1 = b[64 + L];
    for (int mm = 0; mm < NPB; ++mm) {
        float s0 = bb0, s1 = bb1;
#pragma unroll
        for (int k = 0; k < N_FEAT; ++k) { float tv = t[mm][k]; s0 += tv * w0[k]; s1 += tv * w1[k]; }
        h1[((n0 + mm) << 7) + L]      = __float2bfloat16(s0 > 0.f ? s0 : 0.f);
        h1[((n0 + mm) << 7) + 64 + L] = __float2bfloat16(s1 > 0.f ? s1 : 0.f);
    }
}

// ---------------- Fused hidden layer: gather-agg + GEMV (+ optional pool) ----
// 128 threads = 2 waves; each wave owns NPW=4 nodes. wv is SCALARIZED via
// readfirstlane so n0/rowptr/csr stay in SGPRs -> csr reads are s_load on the
// lgkm queue, overlapping the vmcnt hin-gathers (R6's regression was these
// becoming divergent vector loads: two dependent VMEM round-trips per edge).
// Lane L owns feature pair (2L, 2L+1): one bf16x2 (4B) load per edge per lane.
template <bool POOL>
__global__ __launch_bounds__(128) void hidden_layer(
        const bf16* __restrict__ hin, const int2* __restrict__ csr,
        const int* __restrict__ rowptr, const float* __restrict__ We,
        const float* __restrict__ be, const float* __restrict__ W,
        const float* __restrict__ b, bf16* __restrict__ hout,
        const int* __restrict__ batch, float* __restrict__ pool,
        float* __restrict__ cnt) {
    __shared__ float t[NPB][HID];
    int L = threadIdx.x & 63;
    int wv = __builtin_amdgcn_readfirstlane(threadIdx.x >> 6);  // wave-uniform, force SGPR
    int f = L << 1;
    int n0 = blockIdx.x * NPB + wv * NPW;   // scalar
    float we0 = We[f], we1 = We[f + 1], be0 = be[f], be1 = be[f + 1];

    for (int m = 0; m < NPW; ++m) {
        int n = n0 + m;                      // scalar
        int r0 = rowptr[n], r1 = rowptr[n + 1];   // s_load
        float a0 = 0.f, a1 = 0.f;
#pragma unroll 8
        for (int i = r0; i < r1; ++i) {
            int2 sa = csr[i];               // scalar load (uniform address)
            unsigned hh = *(const unsigned*)(hin + ((sa.x << 7) + f));
            float ea = __int_as_float(sa.y);
            float m0 = bflo(hh) + ea * we0 + be0;
            float m1 = bfhi(hh) + ea * we1 + be1;
            a0 += m0 > 0.f ? m0 : 0.f;
            a1 += m1 > 0.f ? m1 : 0.f;
        }
        unsigned hs = *(const unsigned*)(hin + ((n << 7) + f));
        *(float2*)&t[wv * NPW + m][f] = make_float2(a0 + bflo(hs), a1 + bfhi(hs));
    }
    __syncthreads();

    // GEMV: each wave computes its own 4 nodes (no cross-wave sharing)
    float o0[NPW], o1[NPW];
    float bb0 = b[f], bb1 = b[f + 1];
#pragma unroll
    for (int m = 0; m < NPW; ++m) { o0[m] = bb0; o1[m] = bb1; }
    for (int k = 0; k < HID; k += 2) {
        float2 wA = *(const float2*)&W[k * HID + f];
        float2 wB = *(const float2*)&W[(k + 1) * HID + f];
#pragma unroll
        for (int m = 0; m < NPW; ++m) {
            float2 tv = *(const float2*)&t[wv * NPW + m][k];   // ds_read_b64 broadcast
            o0[m] += tv.x * wA.x + tv.y * wB.x;
            o1[m] += tv.x * wA.y + tv.y * wB.y;
        }
    }

    if (!POOL) {
#pragma unroll
        for (int m = 0; m < NPW; ++m) {
            float v0 = o0[m] > 0.f ? o0[m] : 0.f;
            float v1 = o1[m] > 0.f ? o1[m] : 0.f;
            *(unsigned*)(hout + (((n0 + m) << 7) + f)) = packbf(v0, v1);
        }
    } else {
        int g = batch[n0];
        int runstart = n0;
        float p0 = 0.f, p1 = 0.f;
        for (int m = 0; m < NPW; ++m) {
            int n = n0 + m;
            int gn = batch[n];
            if (gn != g) {
                atomicAdd(&pool[g * HID + f], p0);
                atomicAdd(&pool[g * HID + f + 1], p1);
                if (L == 0) atomicAdd(&cnt[g], (float)(n - runstart));
                p0 = p1 = 0.f; g = gn; runstart = n;
            }
            p0 += o0[m] > 0.f ? o0[m] : 0.f;
            p1 += o1[m] > 0.f ? o1[m] : 0.f;
        }
        atomicAdd(&pool[g * HID + f], p0);
        atomicAdd(&pool[g * HID + f + 1], p1);
        if (L == 0) atomicAdd(&cnt[g], (float)(n0 + NPW - runstart));
    }
}

// ---------------- Head ----------------

__global__ void final_kernel(const float* __restrict__ pool, const float* __restrict__ cnt,
                             const float* __restrict__ Wlin, const float* __restrict__ blin,
                             float* __restrict__ out) {
    int idx = threadIdx.x;
    if (idx >= N_GRAPHS * N_CLASS) return;
    int g = idx / N_CLASS, c = idx % N_CLASS;
    float invc = 1.f / fmaxf(cnt[g], 1.f);
    float acc = blin[c];
    for (int j = 0; j < HID; ++j) acc += pool[g * HID + j] * invc * Wlin[j * N_CLASS + c];
    out[idx] = acc;
}

extern "C" void kernel_launch(void* const* d_in, const int* in_sizes, int n_in,
                              void* d_out, int out_size, void* d_ws, size_t ws_size,
                              hipStream_t stream) {
    const float* x    = (const float*)d_in[0];
    const int*   ei   = (const int*)d_in[1];
    const float* ea   = (const float*)d_in[2];
    const int*   batch= (const int*)d_in[3];
    const float* We1  = (const float*)d_in[4];
    const float* be1  = (const float*)d_in[5];
    const float* W1   = (const float*)d_in[6];
    const float* b1   = (const float*)d_in[7];
    const float* We2  = (const float*)d_in[8];
    const float* be2  = (const float*)d_in[9];
    const float* W2   = (const float*)d_in[10];
    const float* b2   = (const float*)d_in[11];
    const float* We3  = (const float*)d_in[12];
    const float* be3  = (const float*)d_in[13];
    const float* W3   = (const float*)d_in[14];
    const float* b3   = (const float*)d_in[15];
    const float* Wlin = (const float*)d_in[16];
    const float* blin = (const float*)d_in[17];

    const int* src = ei;
    const int* dst = ei + N_EDGES;

    // workspace layout (csr first: 8B-aligned at base)
    char* w = (char*)d_ws;
    int2*  csr    = (int2*)w;                    w += sizeof(int2) * (size_t)N_EDGES;
    bf16*  A      = (bf16*)w;                    w += sizeof(bf16) * (size_t)N_NODES * HID;
    bf16*  B      = (bf16*)w;                    w += sizeof(bf16) * (size_t)N_NODES * HID;
    float* pool   = (float*)w;                   w += sizeof(float) * N_GRAPHS * HID;
    float* cnt    = (float*)w;                   w += sizeof(float) * N_GRAPHS;
    int*   rowptr = (int*)w;                     w += sizeof(int) * (N_NODES + 1);
    int*   cursor = (int*)w;                     w += sizeof(int) * N_NODES;
    int*   deg    = (int*)w;                     w += sizeof(int) * N_NODES;
    int*   stmp   = (int*)w;                     w += sizeof(int) * N_NODES;
    int*   bsum   = (int*)w;                     w += sizeof(int) * SCAN_NBLK;

    // ---- CSR build ----
    hipMemsetAsync(deg, 0, sizeof(int) * N_NODES, stream);
    hipMemsetAsync(pool, 0, sizeof(float) * (N_GRAPHS * HID + N_GRAPHS), stream);
    hist_kernel<<<(N_EDGES + 255) / 256, 256, 0, stream>>>(dst, deg);
    scan_phase1<<<SCAN_NBLK, 1024, 0, stream>>>(deg, stmp, bsum);
    scan_phase2<<<1, 128, 0, stream>>>(bsum);
    scan_phase3<<<SCAN_NBLK, 1024, 0, stream>>>(stmp, bsum, rowptr, cursor);
    scatter_kernel<<<(N_EDGES + 255) / 256, 256, 0, stream>>>(src, dst, ea, cursor, csr);

    // ---- Layer 1 (fused) ----
    layer1<<<N_NODES / NPB, 64, 0, stream>>>(x, csr, rowptr, We1, be1, W1, b1, A);

    // ---- Layer 2: A -> B ----
    hidden_layer<false><<<N_NODES / NPB, 128, 0, stream>>>(A, csr, rowptr, We2, be2, W2, b2, B,
                                                           nullptr, nullptr, nullptr);

    // ---- Layer 3: B -> pool (fused) ----
    hidden_layer<true><<<N_NODES / NPB, 128, 0, stream>>>(B, csr, rowptr, We3, be3, W3, b3, nullptr,
                                                          batch, pool, cnt);

    // ---- Head ----
    final_kernel<<<1, 64, 0, stream>>>(pool, cnt, Wlin, blin, (float*)d_out);
}

// Round 8
// 850.918 us; speedup vs baseline: 1.1752x; 1.1141x over previous
//
#include <hip/hip_runtime.h>
#include <hip/hip_bf16.h>

#define N_NODES 100000
#define N_EDGES 1600000
#define N_FEAT 7
#define HID 128
#define N_CLASS 5
#define N_GRAPHS 8
#define NPB1 8   // nodes per block, layer1
#define NPB 4    // nodes per block, hidden layers (128 thr; 25000 blocks)
#define SCAN_NBLK ((N_NODES + 1023) / 1024)   // 98

typedef __hip_bfloat16 bf16;

// ---------------- CSR build (dst-sorted adjacency) ----------------

__global__ void hist_kernel(const int* __restrict__ dst, int* __restrict__ deg) {
    int e = blockIdx.x * blockDim.x + threadIdx.x;
    if (e < N_EDGES) atomicAdd(&deg[dst[e]], 1);
}

__global__ __launch_bounds__(1024) void scan_phase1(const int* __restrict__ deg,
                                                    int* __restrict__ tmp,
                                                    int* __restrict__ bsum) {
    __shared__ int s[1024];
    int tid = threadIdx.x;
    int i = blockIdx.x * 1024 + tid;
    int v = (i < N_NODES) ? deg[i] : 0;
    s[tid] = v;
    __syncthreads();
    for (int off = 1; off < 1024; off <<= 1) {
        int u = (tid >= off) ? s[tid - off] : 0;
        __syncthreads();
        s[tid] += u;
        __syncthreads();
    }
    if (i < N_NODES) tmp[i] = s[tid] - v;            // exclusive
    if (tid == 1023) bsum[blockIdx.x] = s[1023];
}

__global__ __launch_bounds__(128) void scan_phase2(int* __restrict__ bsum) {
    __shared__ int s[128];
    int tid = threadIdx.x;
    int v = (tid < SCAN_NBLK) ? bsum[tid] : 0;
    s[tid] = v;
    __syncthreads();
    for (int off = 1; off < 128; off <<= 1) {
        int u = (tid >= off) ? s[tid - off] : 0;
        __syncthreads();
        s[tid] += u;
        __syncthreads();
    }
    if (tid < SCAN_NBLK) bsum[tid] = s[tid] - v;
}

__global__ __launch_bounds__(1024) void scan_phase3(const int* __restrict__ tmp,
                                                    const int* __restrict__ bsum,
                                                    int* __restrict__ rowptr,
                                                    int* __restrict__ cursor) {
    int i = blockIdx.x * 1024 + threadIdx.x;
    if (i < N_NODES) {
        int r = tmp[i] + bsum[blockIdx.x];
        rowptr[i] = r;
        cursor[i] = r;
    }
    if (i == 0) rowptr[N_NODES] = N_EDGES;
}

__global__ void scatter_kernel(const int* __restrict__ src, const int* __restrict__ dst,
                               const float* __restrict__ ea, int* __restrict__ cursor,
                               int2* __restrict__ csr) {
    int e = blockIdx.x * blockDim.x + threadIdx.x;
    if (e >= N_EDGES) return;
    int d = dst[e];
    int p = atomicAdd(&cursor[d], 1);
    csr[p] = make_int2(src[e], __float_as_int(ea[e]));
}

// ---------------- Layer 1 fused (in=7): edge-agg + GEMV ----------------

__global__ __launch_bounds__(64) void layer1(
        const float* __restrict__ x, const int2* __restrict__ csr,
        const int* __restrict__ rowptr, const float* __restrict__ We,
        const float* __restrict__ be, const float* __restrict__ W,
        const float* __restrict__ b, bf16* __restrict__ h1) {
    __shared__ float t[NPB1][8];
    int L = threadIdx.x;
    int u = L & 7, m = L >> 3;
    int n0 = blockIdx.x * NPB1;
    int n = n0 + m;
    int r0 = rowptr[n], r1 = rowptr[n + 1];
    float we[N_FEAT], bee[N_FEAT], p[N_FEAT];
#pragma unroll
    for (int k = 0; k < N_FEAT; ++k) { we[k] = We[k]; bee[k] = be[k]; p[k] = 0.f; }
    for (int i = r0 + u; i < r1; i += 8) {
        int2 sa = csr[i];
        float a = __int_as_float(sa.y);
        const float* xr = x + (size_t)sa.x * N_FEAT;
#pragma unroll
        for (int k = 0; k < N_FEAT; ++k) {
            float mm = xr[k] + a * we[k] + bee[k];
            p[k] += mm > 0.f ? mm : 0.f;
        }
    }
#pragma unroll
    for (int off = 1; off < 8; off <<= 1)
#pragma unroll
        for (int k = 0; k < N_FEAT; ++k) p[k] += __shfl_xor(p[k], off, 64);
    if (u == 0) {
        const float* xn = x + (size_t)n * N_FEAT;
#pragma unroll
        for (int k = 0; k < N_FEAT; ++k) t[m][k] = p[k] + xn[k];
    }
    __syncthreads();
    float w0[N_FEAT], w1[N_FEAT];
#pragma unroll
    for (int k = 0; k < N_FEAT; ++k) { w0[k] = W[k * HID + L]; w1[k] = W[k * HID + 64 + L]; }
    float bb0 = b[L], bb1 = b[64 + L];
    for (int mm = 0; mm < NPB1; ++mm) {
        float s0 = bb0, s1 = bb1;
#pragma unroll
        for (int k = 0; k < N_FEAT; ++k) { float tv = t[mm][k]; s0 += tv * w0[k]; s1 += tv * w1[k]; }
        h1[((n0 + mm) << 7) + L]      = __float2bfloat16(s0 > 0.f ? s0 : 0.f);
        h1[((n0 + mm) << 7) + 64 + L] = __float2bfloat16(s1 > 0.f ? s1 : 0.f);
    }
}

// ---------------- Fused hidden layer (R4-proven structure, NPB=4) ----------
// 128 threads, thread j = feature j. Node index derives ONLY from blockIdx +
// loop counter -> r0/r1/csr reads are block-uniform scalar loads overlapping
// the per-lane 2B bf16 gathers (this exact loop measured 150us at NPB=8;
// NPB=4 doubles wave count for the latency-bound gather stream).
// POOL=true: layer-3 variant accumulates mean-pool directly, h3 never stored.
template <bool POOL>
__global__ __launch_bounds__(128) void hidden_layer(
        const bf16* __restrict__ hin, const int2* __restrict__ csr,
        const int* __restrict__ rowptr, const float* __restrict__ We,
        const float* __restrict__ be, const float* __restrict__ W,
        const float* __restrict__ b, bf16* __restrict__ hout,
        const int* __restrict__ batch, float* __restrict__ pool,
        float* __restrict__ cnt) {
    __shared__ float t[NPB][HID];
    int j = threadIdx.x;
    int n0 = blockIdx.x * NPB;
    float wej = We[j], bej = be[j];

    for (int m = 0; m < NPB; ++m) {
        int n = n0 + m;
        int r0 = rowptr[n], r1 = rowptr[n + 1];
        float acc = 0.f;
#pragma unroll 4
        for (int i = r0; i < r1; ++i) {
            int2 sa = csr[i];               // block-uniform -> scalar load
            float a = __int_as_float(sa.y);
            float mm = __bfloat162float(hin[(size_t)sa.x * HID + j]) + a * wej + bej;
            acc += mm > 0.f ? mm : 0.f;
        }
        t[m][j] = acc + __bfloat162float(hin[(size_t)n * HID + j]);
    }
    __syncthreads();

    float out[NPB];
    float bb = b[j];
#pragma unroll
    for (int m = 0; m < NPB; ++m) out[m] = bb;
    for (int k = 0; k < HID; ++k) {
        float w = W[k * HID + j];
#pragma unroll
        for (int m = 0; m < NPB; ++m) out[m] += t[m][k] * w;
    }

    if (!POOL) {
#pragma unroll
        for (int m = 0; m < NPB; ++m) {
            float v = out[m];
            hout[(size_t)(n0 + m) * HID + j] = __float2bfloat16(v > 0.f ? v : 0.f);
        }
    } else {
        int g = batch[n0];
        int runstart = n0;
        float p = 0.f;
        for (int m = 0; m < NPB; ++m) {
            int n = n0 + m;
            int gn = batch[n];
            if (gn != g) {
                atomicAdd(&pool[g * HID + j], p);
                if (j == 0) atomicAdd(&cnt[g], (float)(n - runstart));
                p = 0.f; g = gn; runstart = n;
            }
            p += out[m] > 0.f ? out[m] : 0.f;
        }
        atomicAdd(&pool[g * HID + j], p);
        if (j == 0) atomicAdd(&cnt[g], (float)(n0 + NPB - runstart));
    }
}

// ---------------- Head ----------------

__global__ void final_kernel(const float* __restrict__ pool, const float* __restrict__ cnt,
                             const float* __restrict__ Wlin, const float* __restrict__ blin,
                             float* __restrict__ out) {
    int idx = threadIdx.x;
    if (idx >= N_GRAPHS * N_CLASS) return;
    int g = idx / N_CLASS, c = idx % N_CLASS;
    float invc = 1.f / fmaxf(cnt[g], 1.f);
    float acc = blin[c];
    for (int j = 0; j < HID; ++j) acc += pool[g * HID + j] * invc * Wlin[j * N_CLASS + c];
    out[idx] = acc;
}

extern "C" void kernel_launch(void* const* d_in, const int* in_sizes, int n_in,
                              void* d_out, int out_size, void* d_ws, size_t ws_size,
                              hipStream_t stream) {
    const float* x    = (const float*)d_in[0];
    const int*   ei   = (const int*)d_in[1];
    const float* ea   = (const float*)d_in[2];
    const int*   batch= (const int*)d_in[3];
    const float* We1  = (const float*)d_in[4];
    const float* be1  = (const float*)d_in[5];
    const float* W1   = (const float*)d_in[6];
    const float* b1   = (const float*)d_in[7];
    const float* We2  = (const float*)d_in[8];
    const float* be2  = (const float*)d_in[9];
    const float* W2   = (const float*)d_in[10];
    const float* b2   = (const float*)d_in[11];
    const float* We3  = (const float*)d_in[12];
    const float* be3  = (const float*)d_in[13];
    const float* W3   = (const float*)d_in[14];
    const float* b3   = (const float*)d_in[15];
    const float* Wlin = (const float*)d_in[16];
    const float* blin = (const float*)d_in[17];

    const int* src = ei;
    const int* dst = ei + N_EDGES;

    // workspace layout (csr first: 8B-aligned at base)
    char* w = (char*)d_ws;
    int2*  csr    = (int2*)w;                    w += sizeof(int2) * (size_t)N_EDGES;
    bf16*  A      = (bf16*)w;                    w += sizeof(bf16) * (size_t)N_NODES * HID;
    bf16*  B      = (bf16*)w;                    w += sizeof(bf16) * (size_t)N_NODES * HID;
    float* pool   = (float*)w;                   w += sizeof(float) * N_GRAPHS * HID;
    float* cnt    = (float*)w;                   w += sizeof(float) * N_GRAPHS;
    int*   rowptr = (int*)w;                     w += sizeof(int) * (N_NODES + 1);
    int*   cursor = (int*)w;                     w += sizeof(int) * N_NODES;
    int*   deg    = (int*)w;                     w += sizeof(int) * N_NODES;
    int*   stmp   = (int*)w;                     w += sizeof(int) * N_NODES;
    int*   bsum   = (int*)w;                     w += sizeof(int) * SCAN_NBLK;

    // ---- CSR build ----
    hipMemsetAsync(deg, 0, sizeof(int) * N_NODES, stream);
    hipMemsetAsync(pool, 0, sizeof(float) * (N_GRAPHS * HID + N_GRAPHS), stream);
    hist_kernel<<<(N_EDGES + 255) / 256, 256, 0, stream>>>(dst, deg);
    scan_phase1<<<SCAN_NBLK, 1024, 0, stream>>>(deg, stmp, bsum);
    scan_phase2<<<1, 128, 0, stream>>>(bsum);
    scan_phase3<<<SCAN_NBLK, 1024, 0, stream>>>(stmp, bsum, rowptr, cursor);
    scatter_kernel<<<(N_EDGES + 255) / 256, 256, 0, stream>>>(src, dst, ea, cursor, csr);

    // ---- Layer 1 (fused) ----
    layer1<<<N_NODES / NPB1, 64, 0, stream>>>(x, csr, rowptr, We1, be1, W1, b1, A);

    // ---- Layer 2: A -> B ----
    hidden_layer<false><<<N_NODES / NPB, 128, 0, stream>>>(A, csr, rowptr, We2, be2, W2, b2, B,
                                                           nullptr, nullptr, nullptr);

    // ---- Layer 3: B -> pool (fused) ----
    hidden_layer<true><<<N_NODES / NPB, 128, 0, stream>>>(B, csr, rowptr, We3, be3, W3, b3, nullptr,
                                                          batch, pool, cnt);

    // ---- Head ----
    final_kernel<<<1, 64, 0, stream>>>(pool, cnt, Wlin, blin, (float*)d_out);
}

// Round 9
// 689.908 us; speedup vs baseline: 1.4494x; 1.2334x over previous
//
#include <hip/hip_runtime.h>
#include <hip/hip_bf16.h>

#define N_NODES 100000
#define N_EDGES 1600000
#define N_FEAT 7
#define HID 128
#define N_CLASS 5
#define N_GRAPHS 8
#define NPB1 8   // nodes per block, layer1
#define NPB 8    // nodes per block, hidden layers (R4-measured optimum: 150us)
#define SCAN_NBLK ((N_NODES + 1023) / 1024)   // 98

typedef __hip_bfloat16 bf16;

// ---------------- CSR build (dst-sorted adjacency) ----------------

__global__ void hist_kernel(const int* __restrict__ dst, int* __restrict__ deg) {
    int e = blockIdx.x * blockDim.x + threadIdx.x;
    if (e < N_EDGES) atomicAdd(&deg[dst[e]], 1);
}

__global__ __launch_bounds__(1024) void scan_phase1(const int* __restrict__ deg,
                                                    int* __restrict__ tmp,
                                                    int* __restrict__ bsum) {
    __shared__ int s[1024];
    int tid = threadIdx.x;
    int i = blockIdx.x * 1024 + tid;
    int v = (i < N_NODES) ? deg[i] : 0;
    s[tid] = v;
    __syncthreads();
    for (int off = 1; off < 1024; off <<= 1) {
        int u = (tid >= off) ? s[tid - off] : 0;
        __syncthreads();
        s[tid] += u;
        __syncthreads();
    }
    if (i < N_NODES) tmp[i] = s[tid] - v;            // exclusive
    if (tid == 1023) bsum[blockIdx.x] = s[1023];
}

__global__ __launch_bounds__(128) void scan_phase2(int* __restrict__ bsum) {
    __shared__ int s[128];
    int tid = threadIdx.x;
    int v = (tid < SCAN_NBLK) ? bsum[tid] : 0;
    s[tid] = v;
    __syncthreads();
    for (int off = 1; off < 128; off <<= 1) {
        int u = (tid >= off) ? s[tid - off] : 0;
        __syncthreads();
        s[tid] += u;
        __syncthreads();
    }
    if (tid < SCAN_NBLK) bsum[tid] = s[tid] - v;
}

__global__ __launch_bounds__(1024) void scan_phase3(const int* __restrict__ tmp,
                                                    const int* __restrict__ bsum,
                                                    int* __restrict__ rowptr,
                                                    int* __restrict__ cursor) {
    int i = blockIdx.x * 1024 + threadIdx.x;
    if (i < N_NODES) {
        int r = tmp[i] + bsum[blockIdx.x];
        rowptr[i] = r;
        cursor[i] = r;
    }
    if (i == 0) rowptr[N_NODES] = N_EDGES;
}

__global__ void scatter_kernel(const int* __restrict__ src, const int* __restrict__ dst,
                               const float* __restrict__ ea, int* __restrict__ cursor,
                               int2* __restrict__ csr) {
    int e = blockIdx.x * blockDim.x + threadIdx.x;
    if (e >= N_EDGES) return;
    int d = dst[e];
    int p = atomicAdd(&cursor[d], 1);
    csr[p] = make_int2(src[e], __float_as_int(ea[e]));
}

// ---------------- Layer 1 fused (in=7): edge-agg + GEMV ----------------

__global__ __launch_bounds__(64) void layer1(
        const float* __restrict__ x, const int2* __restrict__ csr,
        const int* __restrict__ rowptr, const float* __restrict__ We,
        const float* __restrict__ be, const float* __restrict__ W,
        const float* __restrict__ b, bf16* __restrict__ h1) {
    __shared__ float t[NPB1][8];
    int L = threadIdx.x;
    int u = L & 7, m = L >> 3;
    int n0 = blockIdx.x * NPB1;
    int n = n0 + m;
    int r0 = rowptr[n], r1 = rowptr[n + 1];
    float we[N_FEAT], bee[N_FEAT], p[N_FEAT];
#pragma unroll
    for (int k = 0; k < N_FEAT; ++k) { we[k] = We[k]; bee[k] = be[k]; p[k] = 0.f; }
    for (int i = r0 + u; i < r1; i += 8) {
        int2 sa = csr[i];
        float a = __int_as_float(sa.y);
        const float* xr = x + (size_t)sa.x * N_FEAT;
#pragma unroll
        for (int k = 0; k < N_FEAT; ++k) {
            float mm = xr[k] + a * we[k] + bee[k];
            p[k] += mm > 0.f ? mm : 0.f;
        }
    }
#pragma unroll
    for (int off = 1; off < 8; off <<= 1)
#pragma unroll
        for (int k = 0; k < N_FEAT; ++k) p[k] += __shfl_xor(p[k], off, 64);
    if (u == 0) {
        const float* xn = x + (size_t)n * N_FEAT;
#pragma unroll
        for (int k = 0; k < N_FEAT; ++k) t[m][k] = p[k] + xn[k];
    }
    __syncthreads();
    float w0[N_FEAT], w1[N_FEAT];
#pragma unroll
    for (int k = 0; k < N_FEAT; ++k) { w0[k] = W[k * HID + L]; w1[k] = W[k * HID + 64 + L]; }
    float bb0 = b[L], bb1 = b[64 + L];
    for (int mm = 0; mm < NPB1; ++mm) {
        float s0 = bb0, s1 = bb1;
#pragma unroll
        for (int k = 0; k < N_FEAT; ++k) { float tv = t[mm][k]; s0 += tv * w0[k]; s1 += tv * w1[k]; }
        h1[((n0 + mm) << 7) + L]      = __float2bfloat16(s0 > 0.f ? s0 : 0.f);
        h1[((n0 + mm) << 7) + 64 + L] = __float2bfloat16(s1 > 0.f ? s1 : 0.f);
    }
}

// ---------------- Fused hidden layer (R4-proven structure, NPB=8) ----------
// 128 threads, thread j = feature j. Node index derives ONLY from blockIdx +
// loop counter -> r0/r1/csr reads are block-uniform scalar loads overlapping
// the per-lane 2B bf16 gathers. This exact loop at NPB=8 measured 150us
// (R4); NPB=4 (R8) and all wave-split variants (R5-R7) regressed 2-3x.
// POOL=true: layer-3 variant accumulates mean-pool directly, h3 never stored.
template <bool POOL>
__global__ __launch_bounds__(128) void hidden_layer(
        const bf16* __restrict__ hin, const int2* __restrict__ csr,
        const int* __restrict__ rowptr, const float* __restrict__ We,
        const float* __restrict__ be, const float* __restrict__ W,
        const float* __restrict__ b, bf16* __restrict__ hout,
        const int* __restrict__ batch, float* __restrict__ pool,
        float* __restrict__ cnt) {
    __shared__ float t[NPB][HID];
    int j = threadIdx.x;
    int n0 = blockIdx.x * NPB;
    float wej = We[j], bej = be[j];

    for (int m = 0; m < NPB; ++m) {
        int n = n0 + m;
        int r0 = rowptr[n], r1 = rowptr[n + 1];
        float acc = 0.f;
#pragma unroll 4
        for (int i = r0; i < r1; ++i) {
            int2 sa = csr[i];               // block-uniform -> scalar load
            float a = __int_as_float(sa.y);
            float mm = __bfloat162float(hin[(size_t)sa.x * HID + j]) + a * wej + bej;
            acc += mm > 0.f ? mm : 0.f;
        }
        t[m][j] = acc + __bfloat162float(hin[(size_t)n * HID + j]);
    }
    __syncthreads();

    float out[NPB];
    float bb = b[j];
#pragma unroll
    for (int m = 0; m < NPB; ++m) out[m] = bb;
    for (int k = 0; k < HID; ++k) {
        float w = W[k * HID + j];
#pragma unroll
        for (int m = 0; m < NPB; ++m) out[m] += t[m][k] * w;
    }

    if (!POOL) {
#pragma unroll
        for (int m = 0; m < NPB; ++m) {
            float v = out[m];
            hout[(size_t)(n0 + m) * HID + j] = __float2bfloat16(v > 0.f ? v : 0.f);
        }
    } else {
        int g = batch[n0];
        int runstart = n0;
        float p = 0.f;
        for (int m = 0; m < NPB; ++m) {
            int n = n0 + m;
            int gn = batch[n];
            if (gn != g) {
                atomicAdd(&pool[g * HID + j], p);
                if (j == 0) atomicAdd(&cnt[g], (float)(n - runstart));
                p = 0.f; g = gn; runstart = n;
            }
            p += out[m] > 0.f ? out[m] : 0.f;
        }
        atomicAdd(&pool[g * HID + j], p);
        if (j == 0) atomicAdd(&cnt[g], (float)(n0 + NPB - runstart));
    }
}

// ---------------- Head ----------------

__global__ void final_kernel(const float* __restrict__ pool, const float* __restrict__ cnt,
                             const float* __restrict__ Wlin, const float* __restrict__ blin,
                             float* __restrict__ out) {
    int idx = threadIdx.x;
    if (idx >= N_GRAPHS * N_CLASS) return;
    int g = idx / N_CLASS, c = idx % N_CLASS;
    float invc = 1.f / fmaxf(cnt[g], 1.f);
    float acc = blin[c];
    for (int j = 0; j < HID; ++j) acc += pool[g * HID + j] * invc * Wlin[j * N_CLASS + c];
    out[idx] = acc;
}

extern "C" void kernel_launch(void* const* d_in, const int* in_sizes, int n_in,
                              void* d_out, int out_size, void* d_ws, size_t ws_size,
                              hipStream_t stream) {
    const float* x    = (const float*)d_in[0];
    const int*   ei   = (const int*)d_in[1];
    const float* ea   = (const float*)d_in[2];
    const int*   batch= (const int*)d_in[3];
    const float* We1  = (const float*)d_in[4];
    const float* be1  = (const float*)d_in[5];
    const float* W1   = (const float*)d_in[6];
    const float* b1   = (const float*)d_in[7];
    const float* We2  = (const float*)d_in[8];
    const float* be2  = (const float*)d_in[9];
    const float* W2   = (const float*)d_in[10];
    const float* b2   = (const float*)d_in[11];
    const float* We3  = (const float*)d_in[12];
    const float* be3  = (const float*)d_in[13];
    const float* W3   = (const float*)d_in[14];
    const float* b3   = (const float*)d_in[15];
    const float* Wlin = (const float*)d_in[16];
    const float* blin = (const float*)d_in[17];

    const int* src = ei;
    const int* dst = ei + N_EDGES;

    // workspace layout (csr first: 8B-aligned at base)
    char* w = (char*)d_ws;
    int2*  csr    = (int2*)w;                    w += sizeof(int2) * (size_t)N_EDGES;
    bf16*  A      = (bf16*)w;                    w += sizeof(bf16) * (size_t)N_NODES * HID;
    bf16*  B      = (bf16*)w;                    w += sizeof(bf16) * (size_t)N_NODES * HID;
    float* pool   = (float*)w;                   w += sizeof(float) * N_GRAPHS * HID;
    float* cnt    = (float*)w;                   w += sizeof(float) * N_GRAPHS;
    int*   rowptr = (int*)w;                     w += sizeof(int) * (N_NODES + 1);
    int*   cursor = (int*)w;                     w += sizeof(int) * N_NODES;
    int*   deg    = (int*)w;                     w += sizeof(int) * N_NODES;
    int*   stmp   = (int*)w;                     w += sizeof(int) * N_NODES;
    int*   bsum   = (int*)w;                     w += sizeof(int) * SCAN_NBLK;

    // ---- CSR build ----
    hipMemsetAsync(deg, 0, sizeof(int) * N_NODES, stream);
    hipMemsetAsync(pool, 0, sizeof(float) * (N_GRAPHS * HID + N_GRAPHS), stream);
    hist_kernel<<<(N_EDGES + 255) / 256, 256, 0, stream>>>(dst, deg);
    scan_phase1<<<SCAN_NBLK, 1024, 0, stream>>>(deg, stmp, bsum);
    scan_phase2<<<1, 128, 0, stream>>>(bsum);
    scan_phase3<<<SCAN_NBLK, 1024, 0, stream>>>(stmp, bsum, rowptr, cursor);
    scatter_kernel<<<(N_EDGES + 255) / 256, 256, 0, stream>>>(src, dst, ea, cursor, csr);

    // ---- Layer 1 (fused) ----
    layer1<<<N_NODES / NPB1, 64, 0, stream>>>(x, csr, rowptr, We1, be1, W1, b1, A);

    // ---- Layer 2: A -> B ----
    hidden_layer<false><<<N_NODES / NPB, 128, 0, stream>>>(A, csr, rowptr, We2, be2, W2, b2, B,
                                                           nullptr, nullptr, nullptr);

    // ---- Layer 3: B -> pool (fused) ----
    hidden_layer<true><<<N_NODES / NPB, 128, 0, stream>>>(B, csr, rowptr, We3, be3, W3, b3, nullptr,
                                                          batch, pool, cnt);

    // ---- Head ----
    final_kernel<<<1, 64, 0, stream>>>(pool, cnt, Wlin, blin, (float*)d_out);
}